// Round 6
// baseline (505.469 us; speedup 1.0000x reference)
//
#include <hip/hip_runtime.h>
#include <math.h>

#define INCH 128
#define DH 64     // d*h
#define H  32
#define D  2
#define LAYERS 4
#define OUTC 32

typedef __fp16 half4 __attribute__((ext_vector_type(4)));
typedef float  f32x4 __attribute__((ext_vector_type(4)));

__device__ __forceinline__ float eluf(float v) { return v > 0.f ? v : expm1f(v); }

// ---------------- one-time prep: f16 copies of W1, W2, kron(Wl,Wr) ----------------
__global__ void k_prep(const float* __restrict__ W1, const float* __restrict__ W2,
                       const float* __restrict__ Wleft, const float* __restrict__ Wright,
                       __fp16* __restrict__ W1h, __fp16* __restrict__ W2h,
                       __fp16* __restrict__ Mlrh) {
    int idx = blockIdx.x * blockDim.x + threadIdx.x;
    if (idx < DH * INCH) {
        W1h[idx] = (__fp16)W1[idx];
    } else if (idx < DH * INCH + OUTC * DH) {
        int i = idx - DH * INCH;
        W2h[i] = (__fp16)W2[i];
    } else if (idx < DH * INCH + OUTC * DH + LAYERS * DH * DH) {
        int i = idx - DH * INCH - OUTC * DH;
        int l = i >> 12;
        int r = i & 4095;
        int row = r >> 6;         // sp*32 + c
        int col = r & 63;         // s*32 + cp
        int sp = row >> 5, c = row & 31;
        int s  = col >> 5, cp = col & 31;
        Mlrh[i] = (__fp16)(Wleft[l * 4 + sp * 2 + s] * Wright[l * 1024 + c * 32 + cp]);
    }
}

// ---------------- CSR build (by src) ----------------
__global__ void k_hist(const int* __restrict__ src, int* __restrict__ deg, int E) {
    int e = blockIdx.x * blockDim.x + threadIdx.x;
    if (e < E) atomicAdd(&deg[src[e]], 1);
}

// block partial sums over 1024-elem chunks
__global__ void k_bsum(const int* __restrict__ deg, int* __restrict__ bsum, int N) {
    int b = blockIdx.x, t = threadIdx.x;
    int lane = t & 63, wid = t >> 6;
    int base = b * 1024 + t * 4;
    int s = 0;
    #pragma unroll
    for (int i = 0; i < 4; ++i) {
        int idx = base + i;
        if (idx < N) s += deg[idx];
    }
    #pragma unroll
    for (int ofs = 32; ofs; ofs >>= 1) s += __shfl_xor(s, ofs);
    __shared__ int ws[4];
    if (lane == 0) ws[wid] = s;
    __syncthreads();
    if (t == 0) bsum[b] = ws[0] + ws[1] + ws[2] + ws[3];
}

// single-wave exclusive scan of bsum (B small)
__global__ void k_scan_small(int* __restrict__ bsum, int B) {
    int lane = threadIdx.x;
    int carry = 0;
    for (int base = 0; base < B; base += 64) {
        int i = base + lane;
        int v = (i < B) ? bsum[i] : 0;
        int incl = v;
        #pragma unroll
        for (int ofs = 1; ofs < 64; ofs <<= 1) {
            int tt = __shfl_up(incl, ofs);
            if (lane >= ofs) incl += tt;
        }
        if (i < B) bsum[i] = carry + incl - v;
        carry += __shfl(incl, 63);
    }
}

// final: local exclusive scan + block offset
__global__ void k_scan_final(const int* __restrict__ deg, const int* __restrict__ bsum,
                             int* __restrict__ rowptr, int N) {
    int b = blockIdx.x, t = threadIdx.x;
    int lane = t & 63, wid = t >> 6;
    int base = b * 1024 + t * 4;
    int v[4];
    int s = 0;
    #pragma unroll
    for (int i = 0; i < 4; ++i) {
        int idx = base + i;
        v[i] = (idx < N) ? deg[idx] : 0;
        s += v[i];
    }
    int incl = s;
    #pragma unroll
    for (int ofs = 1; ofs < 64; ofs <<= 1) {
        int tt = __shfl_up(incl, ofs);
        if (lane >= ofs) incl += tt;
    }
    __shared__ int ws[4];
    if (lane == 63) ws[wid] = incl;
    __syncthreads();
    int woff = 0;
    for (int k = 0; k < wid; ++k) woff += ws[k];
    int excl = bsum[b] + woff + incl - s;
    #pragma unroll
    for (int i = 0; i < 4; ++i) {
        int idx = base + i;
        if (idx < N) rowptr[idx] = excl;
        excl += v[i];
        if (idx == N - 1) rowptr[N] = excl;
    }
}

__global__ void k_initcur(const int* __restrict__ rowptr, int* __restrict__ cur, int N) {
    int i = blockIdx.x * blockDim.x + threadIdx.x;
    if (i < N) cur[i] = rowptr[i];
}

// csr_de[pos] = (dst, undirected-edge-id): single 8B scattered write
__global__ void k_scatter(const int* __restrict__ src, const int* __restrict__ dst,
                          int* __restrict__ cur, int2* __restrict__ csr_de, int E) {
    int e = blockIdx.x * blockDim.x + threadIdx.x;
    if (e >= E) return;
    int pos = atomicAdd(&cur[src[e]], 1);
    int EU = E >> 1;
    csr_de[pos] = make_int2(dst[e], (e < EU) ? e : e - EU);
}

// ---------------- MFMA GEMM kernels (16x16x16 f16) ----------------

__global__ __launch_bounds__(256) void k_mlp1(const float* __restrict__ xin,
                                              const __fp16* __restrict__ W1h,
                                              const float* __restrict__ b1,
                                              float* __restrict__ X, int N) {
    __shared__ float xs[16 * INCH];
    __shared__ __fp16 wsh[DH * 132];
    int t = threadIdx.x;
    int node0 = blockIdx.x * 16;
    for (int i = t; i < 16 * INCH / 4; i += 256) {
        int r = i >> 5, c = (i & 31) * 4;
        int node = node0 + r;
        float4 v = (node < N) ? *(const float4*)(xin + (size_t)node * INCH + c)
                              : make_float4(0.f, 0.f, 0.f, 0.f);
        *(float4*)&xs[r * INCH + c] = v;
    }
    for (int i = t; i < DH * INCH / 4; i += 256) {
        int r = i >> 5, c = (i & 31) * 4;
        *(uint2*)&wsh[r * 132 + c] = ((const uint2*)W1h)[i];
    }
    __syncthreads();
    int w = t >> 6, lane = t & 63;
    int oc0 = w * 16;
    int rr = lane & 15, g = lane >> 4;
    f32x4 acc = {0.f, 0.f, 0.f, 0.f};
    #pragma unroll
    for (int ks = 0; ks < INCH / 16; ++ks) {
        float4 xv = *(const float4*)&xs[rr * INCH + ks * 16 + g * 4];
        half4 af = {(__fp16)xv.x, (__fp16)xv.y, (__fp16)xv.z, (__fp16)xv.w};
        half4 bf = *(const half4*)&wsh[(oc0 + rr) * 132 + ks * 16 + g * 4];
        acc = __builtin_amdgcn_mfma_f32_16x16x16f16(af, bf, acc, 0, 0, 0);
    }
    int oc = oc0 + rr;
    float bb = b1[oc];
    #pragma unroll
    for (int r = 0; r < 4; ++r) {
        int node = node0 + g * 4 + r;
        if (node < N) X[(size_t)node * DH + oc] = eluf(acc[r] + bb);
    }
}

// wave per node: P/Q for layer 0
__global__ void k_pq(const float* __restrict__ X, const float* __restrict__ Wsl,
                     float2* __restrict__ P, float2* __restrict__ Q, int N) {
    int wid = (blockIdx.x * blockDim.x + threadIdx.x) >> 6;
    int lane = threadIdx.x & 63;
    if (wid >= N) return;
    float x = X[(size_t)wid * DH + lane];
    float p0 = x * Wsl[lane];
    float q0 = x * Wsl[64 + lane];
    float p1 = x * Wsl[128 + lane];
    float q1 = x * Wsl[192 + lane];
    #pragma unroll
    for (int ofs = 32; ofs; ofs >>= 1) {
        p0 += __shfl_xor(p0, ofs);
        q0 += __shfl_xor(q0, ofs);
        p1 += __shfl_xor(p1, ofs);
        q1 += __shfl_xor(q1, ofs);
    }
    if (lane == 0) {
        P[wid] = make_float2(p0, p1);
        Q[wid] = make_float2(q0, q1);
    }
}

// XW = X @ kron(Wl,Wr)^T ; writes fp32 interleaved + f16 stalk-split arrays
__global__ __launch_bounds__(256) void k_lr(const float* __restrict__ X,
                                            const __fp16* __restrict__ Mlrh_l,
                                            float* __restrict__ XWf,
                                            __fp16* __restrict__ XW0h,
                                            __fp16* __restrict__ XW1h, int N) {
    __shared__ float xs[16 * DH];
    __shared__ __fp16 mlh[DH * 68];
    int t = threadIdx.x;
    int node0 = blockIdx.x * 16;
    for (int i = t; i < 16 * DH / 4; i += 256) {
        int r = i >> 4, c = (i & 15) * 4;
        int node = node0 + r;
        float4 v = (node < N) ? *(const float4*)(X + (size_t)node * DH + c)
                              : make_float4(0.f, 0.f, 0.f, 0.f);
        *(float4*)&xs[r * DH + c] = v;
    }
    for (int i = t; i < DH * DH / 4; i += 256) {
        int r = i >> 4, c = (i & 15) * 4;
        *(uint2*)&mlh[r * 68 + c] = ((const uint2*)Mlrh_l)[i];
    }
    __syncthreads();
    int w = t >> 6, lane = t & 63;
    int oc0 = w * 16;
    int rr = lane & 15, g = lane >> 4;
    f32x4 acc = {0.f, 0.f, 0.f, 0.f};
    #pragma unroll
    for (int ks = 0; ks < DH / 16; ++ks) {
        float4 xv = *(const float4*)&xs[rr * DH + ks * 16 + g * 4];
        half4 af = {(__fp16)xv.x, (__fp16)xv.y, (__fp16)xv.z, (__fp16)xv.w};
        half4 bf = *(const half4*)&mlh[(oc0 + rr) * 68 + ks * 16 + g * 4];
        acc = __builtin_amdgcn_mfma_f32_16x16x16f16(af, bf, acc, 0, 0, 0);
    }
    int oc = oc0 + rr;
    int sp = oc >> 5, c = oc & 31;
    __fp16* __restrict__ XWs = sp ? XW1h : XW0h;
    #pragma unroll
    for (int r = 0; r < 4; ++r) {
        int node = node0 + g * 4 + r;
        if (node < N) {
            XWf[(size_t)node * DH + oc] = acc[r];
            XWs[(size_t)node * H + c] = (__fp16)acc[r];
        }
    }
}

__global__ __launch_bounds__(256) void k_out(const float* __restrict__ X,
                                             const __fp16* __restrict__ W2h,
                                             const float* __restrict__ b2,
                                             float* __restrict__ out, int N) {
    __shared__ float xs[32 * DH];
    __shared__ __fp16 w2s[OUTC * 68];
    int t = threadIdx.x;
    int node0 = blockIdx.x * 32;
    for (int i = t; i < 32 * DH / 4; i += 256) {
        int r = i >> 4, c = (i & 15) * 4;
        int node = node0 + r;
        float4 v = (node < N) ? *(const float4*)(X + (size_t)node * DH + c)
                              : make_float4(0.f, 0.f, 0.f, 0.f);
        *(float4*)&xs[r * DH + c] = v;
    }
    for (int i = t; i < OUTC * DH / 4; i += 256) {
        int r = i >> 4, c = (i & 15) * 4;
        *(uint2*)&w2s[r * 68 + c] = ((const uint2*)W2h)[i];
    }
    __syncthreads();
    int w = t >> 6, lane = t & 63;
    int nt = w >> 1;
    int oc0 = (w & 1) * 16;
    int rr = lane & 15, g = lane >> 4;
    f32x4 acc = {0.f, 0.f, 0.f, 0.f};
    #pragma unroll
    for (int ks = 0; ks < DH / 16; ++ks) {
        float4 xv = *(const float4*)&xs[(nt * 16 + rr) * DH + ks * 16 + g * 4];
        half4 af = {(__fp16)xv.x, (__fp16)xv.y, (__fp16)xv.z, (__fp16)xv.w};
        half4 bf = *(const half4*)&w2s[(oc0 + rr) * 68 + ks * 16 + g * 4];
        acc = __builtin_amdgcn_mfma_f32_16x16x16f16(af, bf, acc, 0, 0, 0);
    }
    int oc = oc0 + rr;
    float bb = b2[oc];
    #pragma unroll
    for (int r = 0; r < 4; ++r) {
        int node = node0 + nt * 16 + g * 4 + r;
        if (node < N) out[(size_t)node * OUTC + oc] = acc[r] + bb;
    }
}

// ---------------- per-layer edge kernels (no atomics) ----------------

// wave per 4 nodes, 16 lanes/node: DG[u,s] = sum over CSR row of tanh(P_u+Q_v)^2
__global__ void k_dg(const float2* __restrict__ P, const float2* __restrict__ Q,
                     const int* __restrict__ rowptr, const int2* __restrict__ csr_de,
                     float2* __restrict__ DG, int N) {
    int wid = (blockIdx.x * blockDim.x + threadIdx.x) >> 6;
    int lane = threadIdx.x & 63;
    int nn = lane >> 4, sub = lane & 15;
    int node = wid * 4 + nn;
    if (node >= N) return;
    float2 Pu = P[node];
    int pos = rowptr[node], end = rowptr[node + 1];
    float sx = 0.f, sy = 0.f;
    for (int i = pos + sub; i < end; i += 16) {
        int v = csr_de[i].x;
        float2 Qv = Q[v];
        float fx = tanhf(Pu.x + Qv.x);
        float fy = tanhf(Pu.y + Qv.y);
        sx += fx * fx;
        sy += fy * fy;
    }
    #pragma unroll
    for (int ofs = 8; ofs; ofs >>= 1) {
        sx += __shfl_xor(sx, ofs);
        sy += __shfl_xor(sy, ofs);
    }
    if (sub == 0) DG[node] = make_float2(sx, sy);
}

// thread per undirected edge: per-stalk weights into separate coalesced arrays
__global__ void k_we(const int* __restrict__ src, const int* __restrict__ dst,
                     const float2* __restrict__ P, const float2* __restrict__ Q,
                     const float2* __restrict__ DG, float* __restrict__ w0,
                     float* __restrict__ w1, int EU) {
    int t = blockIdx.x * blockDim.x + threadIdx.x;
    if (t >= EU) return;
    int u = src[t], v = dst[t];
    float2 Pu = P[u], Qv = Q[v], Pv = P[v], Qu = Q[u];
    float2 gu = DG[u], gv = DG[v];
    float ffx = tanhf(Pu.x + Qv.x), ffy = tanhf(Pu.y + Qv.y);
    float fbx = tanhf(Pv.x + Qu.x), fby = tanhf(Pv.y + Qu.y);
    w0[t] = -ffx * fbx * rsqrtf(gu.x + 1.f) * rsqrtf(gv.x + 1.f);
    w1[t] = -ffy * fby * rsqrtf(gu.y + 1.f) * rsqrtf(gv.y + 1.f);
}

// wave per node, two stalk phases, 8 edge slots x 8 channel lanes (64B row gathers)
__global__ void k_spmm_fin_pq(const float* __restrict__ XWf,
                              const __fp16* __restrict__ XW0h, const __fp16* __restrict__ XW1h,
                              const float* __restrict__ w0, const float* __restrict__ w1,
                              const int* __restrict__ rowptr, const int2* __restrict__ csr_de,
                              const float2* __restrict__ DG, const float* __restrict__ eps_l,
                              const float* __restrict__ Wsn, float* __restrict__ X,
                              float2* __restrict__ P, float2* __restrict__ Q, int N) {
    int wid = (blockIdx.x * blockDim.x + threadIdx.x) >> 6;
    int lane = threadIdx.x & 63;
    if (wid >= N) return;
    int q = lane >> 3;        // edge slot 0..7
    int m = lane & 7;         // channel quad within stalk: ch 4m..4m+3
    int pos = rowptr[wid], end = rowptr[wid + 1];

    float a0x = 0.f, a0y = 0.f, a0z = 0.f, a0w = 0.f;
    float a1x = 0.f, a1y = 0.f, a1z = 0.f, a1w = 0.f;

    // phase 0 (stalk 0)
    for (int base = pos; base < end; base += 8) {
        int idx = base + q;
        bool valid = idx < end;
        int d = 0; float wgt = 0.f;
        if (valid) {
            int2 de = csr_de[idx];
            d = de.x;
            wgt = w0[de.y];
        }
        half4 g = *(const half4*)(XW0h + (size_t)d * H + m * 4);
        a0x += wgt * (float)g.x; a0y += wgt * (float)g.y;
        a0z += wgt * (float)g.z; a0w += wgt * (float)g.w;
    }
    // phase 1 (stalk 1)
    for (int base = pos; base < end; base += 8) {
        int idx = base + q;
        bool valid = idx < end;
        int d = 0; float wgt = 0.f;
        if (valid) {
            int2 de = csr_de[idx];
            d = de.x;
            wgt = w1[de.y];
        }
        half4 g = *(const half4*)(XW1h + (size_t)d * H + m * 4);
        a1x += wgt * (float)g.x; a1y += wgt * (float)g.y;
        a1z += wgt * (float)g.z; a1w += wgt * (float)g.w;
    }
    // reduce across 8 edge slots (xor 8,16,32)
    #pragma unroll
    for (int ofs = 8; ofs <= 32; ofs <<= 1) {
        a0x += __shfl_xor(a0x, ofs); a0y += __shfl_xor(a0y, ofs);
        a0z += __shfl_xor(a0z, ofs); a0w += __shfl_xor(a0w, ofs);
        a1x += __shfl_xor(a1x, ofs); a1y += __shfl_xor(a1y, ofs);
        a1z += __shfl_xor(a1z, ofs); a1w += __shfl_xor(a1w, ofs);
    }
    if (q == 0) {
        float2 dgv = DG[wid];
        float diag0 = dgv.x / (dgv.x + 1.f);
        float diag1 = dgv.y / (dgv.y + 1.f);
        size_t b0 = (size_t)wid * DH + m * 4;
        size_t b1 = b0 + 32;
        float4 xwf0 = *(const float4*)(XWf + b0);
        float4 xwf1 = *(const float4*)(XWf + b1);
        float coeff0 = 1.f + tanhf(eps_l[0]);
        float coeff1 = 1.f + tanhf(eps_l[1]);
        float4 xo0 = *(const float4*)(X + b0);
        float4 xo1 = *(const float4*)(X + b1);
        float4 xn0, xn1;
        xn0.x = coeff0 * xo0.x - eluf(diag0 * xwf0.x + a0x);
        xn0.y = coeff0 * xo0.y - eluf(diag0 * xwf0.y + a0y);
        xn0.z = coeff0 * xo0.z - eluf(diag0 * xwf0.z + a0z);
        xn0.w = coeff0 * xo0.w - eluf(diag0 * xwf0.w + a0w);
        xn1.x = coeff1 * xo1.x - eluf(diag1 * xwf1.x + a1x);
        xn1.y = coeff1 * xo1.y - eluf(diag1 * xwf1.y + a1y);
        xn1.z = coeff1 * xo1.z - eluf(diag1 * xwf1.z + a1z);
        xn1.w = coeff1 * xo1.w - eluf(diag1 * xwf1.w + a1w);
        *(float4*)(X + b0) = xn0;
        *(float4*)(X + b1) = xn1;
        if (Wsn) {
            float4 wa0 = *(const float4*)(Wsn + m * 4);
            float4 wa1 = *(const float4*)(Wsn + 32 + m * 4);
            float4 wb0 = *(const float4*)(Wsn + 64 + m * 4);
            float4 wb1 = *(const float4*)(Wsn + 96 + m * 4);
            float4 wc0 = *(const float4*)(Wsn + 128 + m * 4);
            float4 wc1 = *(const float4*)(Wsn + 160 + m * 4);
            float4 wd0 = *(const float4*)(Wsn + 192 + m * 4);
            float4 wd1 = *(const float4*)(Wsn + 224 + m * 4);
            float p0 = xn0.x * wa0.x + xn0.y * wa0.y + xn0.z * wa0.z + xn0.w * wa0.w
                     + xn1.x * wa1.x + xn1.y * wa1.y + xn1.z * wa1.z + xn1.w * wa1.w;
            float q0 = xn0.x * wb0.x + xn0.y * wb0.y + xn0.z * wb0.z + xn0.w * wb0.w
                     + xn1.x * wb1.x + xn1.y * wb1.y + xn1.z * wb1.z + xn1.w * wb1.w;
            float p1 = xn0.x * wc0.x + xn0.y * wc0.y + xn0.z * wc0.z + xn0.w * wc0.w
                     + xn1.x * wc1.x + xn1.y * wc1.y + xn1.z * wc1.z + xn1.w * wc1.w;
            float q1 = xn0.x * wd0.x + xn0.y * wd0.y + xn0.z * wd0.z + xn0.w * wd0.w
                     + xn1.x * wd1.x + xn1.y * wd1.y + xn1.z * wd1.z + xn1.w * wd1.w;
            #pragma unroll
            for (int ofs = 1; ofs < 8; ofs <<= 1) {
                p0 += __shfl_xor(p0, ofs);
                q0 += __shfl_xor(q0, ofs);
                p1 += __shfl_xor(p1, ofs);
                q1 += __shfl_xor(q1, ofs);
            }
            if (m == 0) {
                P[wid] = make_float2(p0, p1);
                Q[wid] = make_float2(q0, q1);
            }
        }
    }
}

extern "C" void kernel_launch(void* const* d_in, const int* in_sizes, int n_in,
                              void* d_out, int out_size, void* d_ws, size_t ws_size,
                              hipStream_t stream) {
    const float* xin    = (const float*)d_in[0];
    const int*   ei     = (const int*)d_in[1];
    const float* W1     = (const float*)d_in[2];
    const float* b1     = (const float*)d_in[3];
    const float* Wsheaf = (const float*)d_in[4];
    const float* Wleft  = (const float*)d_in[5];
    const float* Wright = (const float*)d_in[6];
    const float* eps    = (const float*)d_in[7];
    const float* W2     = (const float*)d_in[8];
    const float* b2     = (const float*)d_in[9];
    float* out = (float*)d_out;

    int N = in_sizes[0] / INCH;
    int E = in_sizes[1] / 2;
    int EU = E / 2;
    const int* src = ei;
    const int* dst = ei + E;

    size_t off = 0;
    auto alloc = [&](size_t nbytes) {
        char* p = (char*)d_ws + off;
        off += (nbytes + 255) & ~(size_t)255;
        return p;
    };
    float*   X       = (float*)alloc((size_t)N * DH * 4);
    float*   XWf     = (float*)alloc((size_t)N * DH * 4);
    __fp16*  XW0h    = (__fp16*)alloc((size_t)N * H * 2);
    __fp16*  XW1h    = (__fp16*)alloc((size_t)N * H * 2);
    float*   w0      = (float*)alloc((size_t)EU * 4);
    float*   w1      = (float*)alloc((size_t)EU * 4);
    float2*  DG      = (float2*)alloc((size_t)N * 8);
    float2*  P       = (float2*)alloc((size_t)N * 8);
    float2*  Q       = (float2*)alloc((size_t)N * 8);
    int*     deg     = (int*)alloc((size_t)N * 4);
    int*     rowptr  = (int*)alloc(((size_t)N + 1) * 4);
    int*     cur     = (int*)alloc((size_t)N * 4);
    int2*    csr_de  = (int2*)alloc((size_t)E * 8);
    int*     bsum    = (int*)alloc(4096);
    __fp16*  W1h     = (__fp16*)alloc((size_t)DH * INCH * 2);
    __fp16*  W2h     = (__fp16*)alloc((size_t)OUTC * DH * 2);
    __fp16*  Mlrh    = (__fp16*)alloc((size_t)LAYERS * DH * DH * 2);

    int B = (N + 1023) / 1024;

    // one-time prep + CSR build
    int prep_total = DH * INCH + OUTC * DH + LAYERS * DH * DH;
    k_prep<<<(prep_total + 255) / 256, 256, 0, stream>>>(W1, W2, Wleft, Wright, W1h, W2h, Mlrh);
    hipMemsetAsync(deg, 0, (size_t)N * sizeof(int), stream);
    k_hist<<<(E + 255) / 256, 256, 0, stream>>>(src, deg, E);
    k_bsum<<<B, 256, 0, stream>>>(deg, bsum, N);
    k_scan_small<<<1, 64, 0, stream>>>(bsum, B);
    k_scan_final<<<B, 256, 0, stream>>>(deg, bsum, rowptr, N);
    k_initcur<<<(N + 255) / 256, 256, 0, stream>>>(rowptr, cur, N);
    k_scatter<<<(E + 255) / 256, 256, 0, stream>>>(src, dst, cur, csr_de, E);

    k_mlp1<<<(N + 15) / 16, 256, 0, stream>>>(xin, W1h, b1, X, N);
    k_pq<<<(N + 3) / 4, 256, 0, stream>>>(X, Wsheaf, P, Q, N);

    for (int l = 0; l < LAYERS; ++l) {
        k_dg<<<(N + 15) / 16, 256, 0, stream>>>(P, Q, rowptr, csr_de, DG, N);
        k_we<<<(EU + 255) / 256, 256, 0, stream>>>(src, dst, P, Q, DG, w0, w1, EU);
        k_lr<<<(N + 15) / 16, 256, 0, stream>>>(X, Mlrh + (size_t)l * DH * DH, XWf, XW0h, XW1h, N);
        const float* Wsn = (l + 1 < LAYERS) ? (Wsheaf + (l + 1) * 2 * INCH) : nullptr;
        k_spmm_fin_pq<<<(N + 3) / 4, 256, 0, stream>>>(XWf, XW0h, XW1h, w0, w1, rowptr, csr_de,
                                                       DG, eps + l * 2, Wsn, X, P, Q, N);
    }

    k_out<<<(N + 31) / 32, 256, 0, stream>>>(X, W2h, b2, out, N);
}

// Round 8
// 425.170 us; speedup vs baseline: 1.1889x; 1.1889x over previous
//
#include <hip/hip_runtime.h>
#include <math.h>

#define INCH 128
#define DH 64     // d*h
#define H  32
#define D  2
#define LAYERS 4
#define OUTC 32

typedef __fp16 half4 __attribute__((ext_vector_type(4)));
typedef float  f32x4 __attribute__((ext_vector_type(4)));

__device__ __forceinline__ float eluf(float v) { return v > 0.f ? v : expm1f(v); }

// ---------------- one-time prep: f16 copies of W1, W2, kron(Wl,Wr) ----------------
__global__ void k_prep(const float* __restrict__ W1, const float* __restrict__ W2,
                       const float* __restrict__ Wleft, const float* __restrict__ Wright,
                       __fp16* __restrict__ W1h, __fp16* __restrict__ W2h,
                       __fp16* __restrict__ Mlrh) {
    int idx = blockIdx.x * blockDim.x + threadIdx.x;
    if (idx < DH * INCH) {
        W1h[idx] = (__fp16)W1[idx];
    } else if (idx < DH * INCH + OUTC * DH) {
        int i = idx - DH * INCH;
        W2h[i] = (__fp16)W2[i];
    } else if (idx < DH * INCH + OUTC * DH + LAYERS * DH * DH) {
        int i = idx - DH * INCH - OUTC * DH;
        int l = i >> 12;
        int r = i & 4095;
        int row = r >> 6;         // sp*32 + c
        int col = r & 63;         // s*32 + cp
        int sp = row >> 5, c = row & 31;
        int s  = col >> 5, cp = col & 31;
        Mlrh[i] = (__fp16)(Wleft[l * 4 + sp * 2 + s] * Wright[l * 1024 + c * 32 + cp]);
    }
}

// ---------------- CSR build (by src) ----------------
__global__ void k_hist(const int* __restrict__ src, int* __restrict__ deg, int E) {
    int e = blockIdx.x * blockDim.x + threadIdx.x;
    if (e < E) atomicAdd(&deg[src[e]], 1);
}

__global__ void k_bsum(const int* __restrict__ deg, int* __restrict__ bsum, int N) {
    int b = blockIdx.x, t = threadIdx.x;
    int lane = t & 63, wid = t >> 6;
    int base = b * 1024 + t * 4;
    int s = 0;
    #pragma unroll
    for (int i = 0; i < 4; ++i) {
        int idx = base + i;
        if (idx < N) s += deg[idx];
    }
    #pragma unroll
    for (int ofs = 32; ofs; ofs >>= 1) s += __shfl_xor(s, ofs);
    __shared__ int ws[4];
    if (lane == 0) ws[wid] = s;
    __syncthreads();
    if (t == 0) bsum[b] = ws[0] + ws[1] + ws[2] + ws[3];
}

__global__ void k_scan_small(int* __restrict__ bsum, int B) {
    int lane = threadIdx.x;
    int carry = 0;
    for (int base = 0; base < B; base += 64) {
        int i = base + lane;
        int v = (i < B) ? bsum[i] : 0;
        int incl = v;
        #pragma unroll
        for (int ofs = 1; ofs < 64; ofs <<= 1) {
            int tt = __shfl_up(incl, ofs);
            if (lane >= ofs) incl += tt;
        }
        if (i < B) bsum[i] = carry + incl - v;
        carry += __shfl(incl, 63);
    }
}

__global__ void k_scan_final(const int* __restrict__ deg, const int* __restrict__ bsum,
                             int* __restrict__ rowptr, int N) {
    int b = blockIdx.x, t = threadIdx.x;
    int lane = t & 63, wid = t >> 6;
    int base = b * 1024 + t * 4;
    int v[4];
    int s = 0;
    #pragma unroll
    for (int i = 0; i < 4; ++i) {
        int idx = base + i;
        v[i] = (idx < N) ? deg[idx] : 0;
        s += v[i];
    }
    int incl = s;
    #pragma unroll
    for (int ofs = 1; ofs < 64; ofs <<= 1) {
        int tt = __shfl_up(incl, ofs);
        if (lane >= ofs) incl += tt;
    }
    __shared__ int ws[4];
    if (lane == 63) ws[wid] = incl;
    __syncthreads();
    int woff = 0;
    for (int k = 0; k < wid; ++k) woff += ws[k];
    int excl = bsum[b] + woff + incl - s;
    #pragma unroll
    for (int i = 0; i < 4; ++i) {
        int idx = base + i;
        if (idx < N) rowptr[idx] = excl;
        excl += v[i];
        if (idx == N - 1) rowptr[N] = excl;
    }
}

__global__ void k_initcur(const int* __restrict__ rowptr, int* __restrict__ cur, int N) {
    int i = blockIdx.x * blockDim.x + threadIdx.x;
    if (i < N) cur[i] = rowptr[i];
}

// csr_dst[pos] = dst[e]  (4B scattered write)
__global__ void k_scatter(const int* __restrict__ src, const int* __restrict__ dst,
                          int* __restrict__ cur, int* __restrict__ csr_dst, int E) {
    int e = blockIdx.x * blockDim.x + threadIdx.x;
    if (e >= E) return;
    int pos = atomicAdd(&cur[src[e]], 1);
    csr_dst[pos] = dst[e];
}

// ---------------- MFMA GEMM kernels (16x16x16 f16) ----------------

__global__ __launch_bounds__(256) void k_mlp1(const float* __restrict__ xin,
                                              const __fp16* __restrict__ W1h,
                                              const float* __restrict__ b1,
                                              float* __restrict__ X, int N) {
    __shared__ float xs[16 * INCH];
    __shared__ __fp16 wsh[DH * 132];
    int t = threadIdx.x;
    int node0 = blockIdx.x * 16;
    for (int i = t; i < 16 * INCH / 4; i += 256) {
        int r = i >> 5, c = (i & 31) * 4;
        int node = node0 + r;
        f32x4 v = (node < N) ? __builtin_nontemporal_load((const f32x4*)(xin + (size_t)node * INCH + c))
                             : (f32x4){0.f, 0.f, 0.f, 0.f};
        *(f32x4*)&xs[r * INCH + c] = v;
    }
    for (int i = t; i < DH * INCH / 4; i += 256) {
        int r = i >> 5, c = (i & 31) * 4;
        *(uint2*)&wsh[r * 132 + c] = ((const uint2*)W1h)[i];
    }
    __syncthreads();
    int w = t >> 6, lane = t & 63;
    int oc0 = w * 16;
    int rr = lane & 15, g = lane >> 4;
    f32x4 acc = {0.f, 0.f, 0.f, 0.f};
    #pragma unroll
    for (int ks = 0; ks < INCH / 16; ++ks) {
        f32x4 xv = *(const f32x4*)&xs[rr * INCH + ks * 16 + g * 4];
        half4 af = {(__fp16)xv.x, (__fp16)xv.y, (__fp16)xv.z, (__fp16)xv.w};
        half4 bf = *(const half4*)&wsh[(oc0 + rr) * 132 + ks * 16 + g * 4];
        acc = __builtin_amdgcn_mfma_f32_16x16x16f16(af, bf, acc, 0, 0, 0);
    }
    int oc = oc0 + rr;
    float bb = b1[oc];
    #pragma unroll
    for (int r = 0; r < 4; ++r) {
        int node = node0 + g * 4 + r;
        if (node < N) X[(size_t)node * DH + oc] = eluf(acc[r] + bb);
    }
}

// wave per node: layer-0 P/Q -> PQ4 = (p0,p1,q0,q1)
__global__ void k_pq(const float* __restrict__ X, const float* __restrict__ Wsl,
                     float4* __restrict__ PQ4, int N) {
    int wid = (blockIdx.x * blockDim.x + threadIdx.x) >> 6;
    int lane = threadIdx.x & 63;
    if (wid >= N) return;
    float x = X[(size_t)wid * DH + lane];
    float p0 = x * Wsl[lane];
    float q0 = x * Wsl[64 + lane];
    float p1 = x * Wsl[128 + lane];
    float q1 = x * Wsl[192 + lane];
    #pragma unroll
    for (int ofs = 32; ofs; ofs >>= 1) {
        p0 += __shfl_xor(p0, ofs);
        q0 += __shfl_xor(q0, ofs);
        p1 += __shfl_xor(p1, ofs);
        q1 += __shfl_xor(q1, ofs);
    }
    if (lane == 0) PQ4[wid] = make_float4(p0, p1, q0, q1);
}

// XW = X @ kron(Wl,Wr)^T ; f16 stalk-split outputs only
__global__ __launch_bounds__(256) void k_lr(const float* __restrict__ X,
                                            const __fp16* __restrict__ Mlrh_l,
                                            __fp16* __restrict__ XW0h,
                                            __fp16* __restrict__ XW1h, int N) {
    __shared__ float xs[16 * DH];
    __shared__ __fp16 mlh[DH * 68];
    int t = threadIdx.x;
    int node0 = blockIdx.x * 16;
    for (int i = t; i < 16 * DH / 4; i += 256) {
        int r = i >> 4, c = (i & 15) * 4;
        int node = node0 + r;
        f32x4 v = (node < N) ? __builtin_nontemporal_load((const f32x4*)(X + (size_t)node * DH + c))
                             : (f32x4){0.f, 0.f, 0.f, 0.f};
        *(f32x4*)&xs[r * DH + c] = v;
    }
    for (int i = t; i < DH * DH / 4; i += 256) {
        int r = i >> 4, c = (i & 15) * 4;
        *(uint2*)&mlh[r * 68 + c] = ((const uint2*)Mlrh_l)[i];
    }
    __syncthreads();
    int w = t >> 6, lane = t & 63;
    int oc0 = w * 16;
    int rr = lane & 15, g = lane >> 4;
    f32x4 acc = {0.f, 0.f, 0.f, 0.f};
    #pragma unroll
    for (int ks = 0; ks < DH / 16; ++ks) {
        f32x4 xv = *(const f32x4*)&xs[rr * DH + ks * 16 + g * 4];
        half4 af = {(__fp16)xv.x, (__fp16)xv.y, (__fp16)xv.z, (__fp16)xv.w};
        half4 bf = *(const half4*)&mlh[(oc0 + rr) * 68 + ks * 16 + g * 4];
        acc = __builtin_amdgcn_mfma_f32_16x16x16f16(af, bf, acc, 0, 0, 0);
    }
    int oc = oc0 + rr;
    int sp = oc >> 5, c = oc & 31;
    __fp16* __restrict__ XWs = sp ? XW1h : XW0h;
    #pragma unroll
    for (int r = 0; r < 4; ++r) {
        int node = node0 + g * 4 + r;
        if (node < N) XWs[(size_t)node * H + c] = (__fp16)acc[r];
    }
}

__global__ __launch_bounds__(256) void k_out(const float* __restrict__ X,
                                             const __fp16* __restrict__ W2h,
                                             const float* __restrict__ b2,
                                             float* __restrict__ out, int N) {
    __shared__ float xs[32 * DH];
    __shared__ __fp16 w2s[OUTC * 68];
    int t = threadIdx.x;
    int node0 = blockIdx.x * 32;
    for (int i = t; i < 32 * DH / 4; i += 256) {
        int r = i >> 4, c = (i & 15) * 4;
        int node = node0 + r;
        f32x4 v = (node < N) ? __builtin_nontemporal_load((const f32x4*)(X + (size_t)node * DH + c))
                             : (f32x4){0.f, 0.f, 0.f, 0.f};
        *(f32x4*)&xs[r * DH + c] = v;
    }
    for (int i = t; i < OUTC * DH / 4; i += 256) {
        int r = i >> 4, c = (i & 15) * 4;
        *(uint2*)&w2s[r * 68 + c] = ((const uint2*)W2h)[i];
    }
    __syncthreads();
    int w = t >> 6, lane = t & 63;
    int nt = w >> 1;
    int oc0 = (w & 1) * 16;
    int rr = lane & 15, g = lane >> 4;
    f32x4 acc = {0.f, 0.f, 0.f, 0.f};
    #pragma unroll
    for (int ks = 0; ks < DH / 16; ++ks) {
        f32x4 xv = *(const f32x4*)&xs[(nt * 16 + rr) * DH + ks * 16 + g * 4];
        half4 af = {(__fp16)xv.x, (__fp16)xv.y, (__fp16)xv.z, (__fp16)xv.w};
        half4 bf = *(const half4*)&w2s[(oc0 + rr) * 68 + ks * 16 + g * 4];
        acc = __builtin_amdgcn_mfma_f32_16x16x16f16(af, bf, acc, 0, 0, 0);
    }
    int oc = oc0 + rr;
    float bb = b2[oc];
    #pragma unroll
    for (int r = 0; r < 4; ++r) {
        int node = node0 + nt * 16 + g * 4 + r;
        if (node < N) out[(size_t)node * OUTC + oc] = acc[r] + bb;
    }
}

// ---------------- per-layer edge kernels ----------------

// wave per 4 nodes, 16 lanes/node: DG[u] = sum over row of tanh(P_u+Q_v)^2 (both stalks)
__global__ void k_dg(const float4* __restrict__ PQ4, const int* __restrict__ rowptr,
                     const int* __restrict__ csr_dst, float2* __restrict__ DG, int N) {
    int wid = (blockIdx.x * blockDim.x + threadIdx.x) >> 6;
    int lane = threadIdx.x & 63;
    int nn = lane >> 4, sub = lane & 15;
    int node = wid * 4 + nn;
    if (node >= N) return;
    float4 pqu = PQ4[node];
    int pos = rowptr[node], end = rowptr[node + 1];
    float sx = 0.f, sy = 0.f;
    for (int i = pos + sub; i < end; i += 16) {
        int v = __builtin_nontemporal_load(csr_dst + i);
        float4 pqv = PQ4[v];
        float fx = tanhf(pqu.x + pqv.z);
        float fy = tanhf(pqu.y + pqv.w);
        sx += fx * fx;
        sy += fy * fy;
    }
    #pragma unroll
    for (int ofs = 8; ofs; ofs >>= 1) {
        sx += __shfl_xor(sx, ofs);
        sy += __shfl_xor(sy, ofs);
    }
    if (sub == 0) DG[node] = make_float2(sx, sy);
}

// wave per node: on-the-fly weights (lane-parallel, shfl-distributed),
// 8 edge slots x 8 channel lanes, both stalks; fused elu/residual + next-layer P/Q
__global__ void k_spmm_fin_pq(const __fp16* __restrict__ XW0h, const __fp16* __restrict__ XW1h,
                              const float4* __restrict__ PQ4, const int* __restrict__ rowptr,
                              const int* __restrict__ csr_dst, const float2* __restrict__ DG,
                              const float* __restrict__ eps_l, const float* __restrict__ Wsn,
                              float* __restrict__ X, float4* __restrict__ PQ4n, int N) {
    int wid = (blockIdx.x * blockDim.x + threadIdx.x) >> 6;
    int lane = threadIdx.x & 63;
    if (wid >= N) return;
    int q = lane >> 3;        // edge slot 0..7
    int m = lane & 7;         // channel quad within stalk
    float4 pqu = PQ4[wid];
    float2 gu = DG[wid];
    float dinv0 = rsqrtf(gu.x + 1.f), dinv1 = rsqrtf(gu.y + 1.f);
    int pos = rowptr[wid], end = rowptr[wid + 1];

    float a0x = 0.f, a0y = 0.f, a0z = 0.f, a0w = 0.f;
    float a1x = 0.f, a1y = 0.f, a1z = 0.f, a1w = 0.f;

    for (int chunk = pos; chunk < end; chunk += 64) {
        // lane-parallel weight precompute: lane handles edge chunk+lane
        int myidx = chunk + lane;
        int dmy = 0;
        float w0my = 0.f, w1my = 0.f;
        if (myidx < end) {
            dmy = __builtin_nontemporal_load(csr_dst + myidx);
            float4 pqd = PQ4[dmy];
            float2 gd = DG[dmy];
            float ff0 = tanhf(pqu.x + pqd.z), fb0 = tanhf(pqd.x + pqu.z);
            float ff1 = tanhf(pqu.y + pqd.w), fb1 = tanhf(pqd.y + pqu.w);
            w0my = -ff0 * fb0 * dinv0 * rsqrtf(gd.x + 1.f);
            w1my = -ff1 * fb1 * dinv1 * rsqrtf(gd.y + 1.f);
        }
        int lim = end - chunk; if (lim > 64) lim = 64;
        for (int b = 0; b < lim; b += 8) {
            int sl = b + q;
            int d      = __shfl(dmy, sl);
            float w0e  = __shfl(w0my, sl);   // 0 for sl >= row length
            float w1e  = __shfl(w1my, sl);
            half4 g0 = *(const half4*)(XW0h + (size_t)d * H + m * 4);
            half4 g1 = *(const half4*)(XW1h + (size_t)d * H + m * 4);
            a0x += w0e * (float)g0.x; a0y += w0e * (float)g0.y;
            a0z += w0e * (float)g0.z; a0w += w0e * (float)g0.w;
            a1x += w1e * (float)g1.x; a1y += w1e * (float)g1.y;
            a1z += w1e * (float)g1.z; a1w += w1e * (float)g1.w;
        }
    }
    // reduce across 8 edge slots
    #pragma unroll
    for (int ofs = 8; ofs <= 32; ofs <<= 1) {
        a0x += __shfl_xor(a0x, ofs); a0y += __shfl_xor(a0y, ofs);
        a0z += __shfl_xor(a0z, ofs); a0w += __shfl_xor(a0w, ofs);
        a1x += __shfl_xor(a1x, ofs); a1y += __shfl_xor(a1y, ofs);
        a1z += __shfl_xor(a1z, ofs); a1w += __shfl_xor(a1w, ofs);
    }
    if (q == 0) {
        float diag0 = gu.x / (gu.x + 1.f);
        float diag1 = gu.y / (gu.y + 1.f);
        half4 xw0 = *(const half4*)(XW0h + (size_t)wid * H + m * 4);
        half4 xw1 = *(const half4*)(XW1h + (size_t)wid * H + m * 4);
        size_t b0 = (size_t)wid * DH + m * 4;
        size_t b1 = b0 + 32;
        float coeff0 = 1.f + tanhf(eps_l[0]);
        float coeff1 = 1.f + tanhf(eps_l[1]);
        f32x4 xo0 = __builtin_nontemporal_load((const f32x4*)(X + b0));
        f32x4 xo1 = __builtin_nontemporal_load((const f32x4*)(X + b1));
        f32x4 xn0, xn1;
        xn0.x = coeff0 * xo0.x - eluf(diag0 * (float)xw0.x + a0x);
        xn0.y = coeff0 * xo0.y - eluf(diag0 * (float)xw0.y + a0y);
        xn0.z = coeff0 * xo0.z - eluf(diag0 * (float)xw0.z + a0z);
        xn0.w = coeff0 * xo0.w - eluf(diag0 * (float)xw0.w + a0w);
        xn1.x = coeff1 * xo1.x - eluf(diag1 * (float)xw1.x + a1x);
        xn1.y = coeff1 * xo1.y - eluf(diag1 * (float)xw1.y + a1y);
        xn1.z = coeff1 * xo1.z - eluf(diag1 * (float)xw1.z + a1z);
        xn1.w = coeff1 * xo1.w - eluf(diag1 * (float)xw1.w + a1w);
        __builtin_nontemporal_store(xn0, (f32x4*)(X + b0));
        __builtin_nontemporal_store(xn1, (f32x4*)(X + b1));
        if (Wsn) {
            f32x4 wa0 = *(const f32x4*)(Wsn + m * 4);
            f32x4 wa1 = *(const f32x4*)(Wsn + 32 + m * 4);
            f32x4 wb0 = *(const f32x4*)(Wsn + 64 + m * 4);
            f32x4 wb1 = *(const f32x4*)(Wsn + 96 + m * 4);
            f32x4 wc0 = *(const f32x4*)(Wsn + 128 + m * 4);
            f32x4 wc1 = *(const f32x4*)(Wsn + 160 + m * 4);
            f32x4 wd0 = *(const f32x4*)(Wsn + 192 + m * 4);
            f32x4 wd1 = *(const f32x4*)(Wsn + 224 + m * 4);
            float p0 = xn0.x * wa0.x + xn0.y * wa0.y + xn0.z * wa0.z + xn0.w * wa0.w
                     + xn1.x * wa1.x + xn1.y * wa1.y + xn1.z * wa1.z + xn1.w * wa1.w;
            float q0 = xn0.x * wb0.x + xn0.y * wb0.y + xn0.z * wb0.z + xn0.w * wb0.w
                     + xn1.x * wb1.x + xn1.y * wb1.y + xn1.z * wb1.z + xn1.w * wb1.w;
            float p1 = xn0.x * wc0.x + xn0.y * wc0.y + xn0.z * wc0.z + xn0.w * wc0.w
                     + xn1.x * wc1.x + xn1.y * wc1.y + xn1.z * wc1.z + xn1.w * wc1.w;
            float q1 = xn0.x * wd0.x + xn0.y * wd0.y + xn0.z * wd0.z + xn0.w * wd0.w
                     + xn1.x * wd1.x + xn1.y * wd1.y + xn1.z * wd1.z + xn1.w * wd1.w;
            #pragma unroll
            for (int ofs = 1; ofs < 8; ofs <<= 1) {
                p0 += __shfl_xor(p0, ofs);
                q0 += __shfl_xor(q0, ofs);
                p1 += __shfl_xor(p1, ofs);
                q1 += __shfl_xor(q1, ofs);
            }
            if (m == 0) PQ4n[wid] = make_float4(p0, p1, q0, q1);
        }
    }
}

extern "C" void kernel_launch(void* const* d_in, const int* in_sizes, int n_in,
                              void* d_out, int out_size, void* d_ws, size_t ws_size,
                              hipStream_t stream) {
    const float* xin    = (const float*)d_in[0];
    const int*   ei     = (const int*)d_in[1];
    const float* W1     = (const float*)d_in[2];
    const float* b1     = (const float*)d_in[3];
    const float* Wsheaf = (const float*)d_in[4];
    const float* Wleft  = (const float*)d_in[5];
    const float* Wright = (const float*)d_in[6];
    const float* eps    = (const float*)d_in[7];
    const float* W2     = (const float*)d_in[8];
    const float* b2     = (const float*)d_in[9];
    float* out = (float*)d_out;

    int N = in_sizes[0] / INCH;
    int E = in_sizes[1] / 2;
    const int* src = ei;
    const int* dst = ei + E;

    size_t off = 0;
    auto alloc = [&](size_t nbytes) {
        char* p = (char*)d_ws + off;
        off += (nbytes + 255) & ~(size_t)255;
        return p;
    };
    float*   X       = (float*)alloc((size_t)N * DH * 4);
    __fp16*  XW0h    = (__fp16*)alloc((size_t)N * H * 2);
    __fp16*  XW1h    = (__fp16*)alloc((size_t)N * H * 2);
    float2*  DG      = (float2*)alloc((size_t)N * 8);
    float4*  PQ4a    = (float4*)alloc((size_t)N * 16);
    float4*  PQ4b    = (float4*)alloc((size_t)N * 16);
    int*     deg     = (int*)alloc((size_t)N * 4);
    int*     rowptr  = (int*)alloc(((size_t)N + 1) * 4);
    int*     cur     = (int*)alloc((size_t)N * 4);
    int*     csr_dst = (int*)alloc((size_t)E * 4);
    int*     bsum    = (int*)alloc(4096);
    __fp16*  W1h     = (__fp16*)alloc((size_t)DH * INCH * 2);
    __fp16*  W2h     = (__fp16*)alloc((size_t)OUTC * DH * 2);
    __fp16*  Mlrh    = (__fp16*)alloc((size_t)LAYERS * DH * DH * 2);

    int B = (N + 1023) / 1024;

    // one-time prep + CSR build
    int prep_total = DH * INCH + OUTC * DH + LAYERS * DH * DH;
    k_prep<<<(prep_total + 255) / 256, 256, 0, stream>>>(W1, W2, Wleft, Wright, W1h, W2h, Mlrh);
    hipMemsetAsync(deg, 0, (size_t)N * sizeof(int), stream);
    k_hist<<<(E + 255) / 256, 256, 0, stream>>>(src, deg, E);
    k_bsum<<<B, 256, 0, stream>>>(deg, bsum, N);
    k_scan_small<<<1, 64, 0, stream>>>(bsum, B);
    k_scan_final<<<B, 256, 0, stream>>>(deg, bsum, rowptr, N);
    k_initcur<<<(N + 255) / 256, 256, 0, stream>>>(rowptr, cur, N);
    k_scatter<<<(E + 255) / 256, 256, 0, stream>>>(src, dst, cur, csr_dst, E);

    k_mlp1<<<(N + 15) / 16, 256, 0, stream>>>(xin, W1h, b1, X, N);
    k_pq<<<(N + 3) / 4, 256, 0, stream>>>(X, Wsheaf, PQ4a, N);

    float4* PQcur = PQ4a;
    float4* PQnext = PQ4b;
    for (int l = 0; l < LAYERS; ++l) {
        k_dg<<<(N + 15) / 16, 256, 0, stream>>>(PQcur, rowptr, csr_dst, DG, N);
        k_lr<<<(N + 15) / 16, 256, 0, stream>>>(X, Mlrh + (size_t)l * DH * DH, XW0h, XW1h, N);
        const float* Wsn = (l + 1 < LAYERS) ? (Wsheaf + (l + 1) * 2 * INCH) : nullptr;
        k_spmm_fin_pq<<<(N + 3) / 4, 256, 0, stream>>>(XW0h, XW1h, PQcur, rowptr, csr_dst,
                                                       DG, eps + l * 2, Wsn, X, PQnext, N);
        float4* tmp = PQcur; PQcur = PQnext; PQnext = tmp;
    }

    k_out<<<(N + 31) / 32, 256, 0, stream>>>(X, W2h, b2, out, N);
}

// Round 9
// 408.304 us; speedup vs baseline: 1.2380x; 1.0413x over previous
//
#include <hip/hip_runtime.h>
#include <math.h>

#define INCH 128
#define DH 64     // d*h
#define H  32
#define D  2
#define LAYERS 4
#define OUTC 32

typedef __fp16 half4 __attribute__((ext_vector_type(4)));
typedef float  f32x4 __attribute__((ext_vector_type(4)));

__device__ __forceinline__ float eluf(float v) { return v > 0.f ? v : expm1f(v); }

// fast tanh: (e^2x - 1) * rcp(e^2x + 1), hw exp2 + hw rcp; clamp avoids inf/inf
__device__ __forceinline__ float ftanh(float x) {
    float xc = fminf(9.0f, fmaxf(-9.0f, x));
    float e2 = __builtin_amdgcn_exp2f(xc * 2.885390081777927f);  // e^(2x)
    return (e2 - 1.0f) * __builtin_amdgcn_rcpf(e2 + 1.0f);
}

// ---------------- one-time prep: f16 copies of W1, W2, kron(Wl,Wr) ----------------
__global__ void k_prep(const float* __restrict__ W1, const float* __restrict__ W2,
                       const float* __restrict__ Wleft, const float* __restrict__ Wright,
                       __fp16* __restrict__ W1h, __fp16* __restrict__ W2h,
                       __fp16* __restrict__ Mlrh) {
    int idx = blockIdx.x * blockDim.x + threadIdx.x;
    if (idx < DH * INCH) {
        W1h[idx] = (__fp16)W1[idx];
    } else if (idx < DH * INCH + OUTC * DH) {
        int i = idx - DH * INCH;
        W2h[i] = (__fp16)W2[i];
    } else if (idx < DH * INCH + OUTC * DH + LAYERS * DH * DH) {
        int i = idx - DH * INCH - OUTC * DH;
        int l = i >> 12;
        int r = i & 4095;
        int row = r >> 6;         // sp*32 + c
        int col = r & 63;         // s*32 + cp
        int sp = row >> 5, c = row & 31;
        int s  = col >> 5, cp = col & 31;
        Mlrh[i] = (__fp16)(Wleft[l * 4 + sp * 2 + s] * Wright[l * 1024 + c * 32 + cp]);
    }
}

// ---------------- CSR build (by src) ----------------
__global__ void k_hist(const int* __restrict__ src, int* __restrict__ deg, int E) {
    int e = blockIdx.x * blockDim.x + threadIdx.x;
    if (e < E) atomicAdd(&deg[src[e]], 1);
}

__global__ void k_bsum(const int* __restrict__ deg, int* __restrict__ bsum, int N) {
    int b = blockIdx.x, t = threadIdx.x;
    int lane = t & 63, wid = t >> 6;
    int base = b * 1024 + t * 4;
    int s = 0;
    #pragma unroll
    for (int i = 0; i < 4; ++i) {
        int idx = base + i;
        if (idx < N) s += deg[idx];
    }
    #pragma unroll
    for (int ofs = 32; ofs; ofs >>= 1) s += __shfl_xor(s, ofs);
    __shared__ int ws[4];
    if (lane == 0) ws[wid] = s;
    __syncthreads();
    if (t == 0) bsum[b] = ws[0] + ws[1] + ws[2] + ws[3];
}

__global__ void k_scan_small(int* __restrict__ bsum, int B) {
    int lane = threadIdx.x;
    int carry = 0;
    for (int base = 0; base < B; base += 64) {
        int i = base + lane;
        int v = (i < B) ? bsum[i] : 0;
        int incl = v;
        #pragma unroll
        for (int ofs = 1; ofs < 64; ofs <<= 1) {
            int tt = __shfl_up(incl, ofs);
            if (lane >= ofs) incl += tt;
        }
        if (i < B) bsum[i] = carry + incl - v;
        carry += __shfl(incl, 63);
    }
}

// final: local exclusive scan + block offset; also writes cur = rowptr
__global__ void k_scan_final(const int* __restrict__ deg, const int* __restrict__ bsum,
                             int* __restrict__ rowptr, int* __restrict__ cur, int N) {
    int b = blockIdx.x, t = threadIdx.x;
    int lane = t & 63, wid = t >> 6;
    int base = b * 1024 + t * 4;
    int v[4];
    int s = 0;
    #pragma unroll
    for (int i = 0; i < 4; ++i) {
        int idx = base + i;
        v[i] = (idx < N) ? deg[idx] : 0;
        s += v[i];
    }
    int incl = s;
    #pragma unroll
    for (int ofs = 1; ofs < 64; ofs <<= 1) {
        int tt = __shfl_up(incl, ofs);
        if (lane >= ofs) incl += tt;
    }
    __shared__ int ws[4];
    if (lane == 63) ws[wid] = incl;
    __syncthreads();
    int woff = 0;
    for (int k = 0; k < wid; ++k) woff += ws[k];
    int excl = bsum[b] + woff + incl - s;
    #pragma unroll
    for (int i = 0; i < 4; ++i) {
        int idx = base + i;
        if (idx < N) { rowptr[idx] = excl; cur[idx] = excl; }
        excl += v[i];
        if (idx == N - 1) rowptr[N] = excl;
    }
}

// csr_dst[pos] = dst[e]  (4B scattered write)
__global__ void k_scatter(const int* __restrict__ src, const int* __restrict__ dst,
                          int* __restrict__ cur, int* __restrict__ csr_dst, int E) {
    int e = blockIdx.x * blockDim.x + threadIdx.x;
    if (e >= E) return;
    int pos = atomicAdd(&cur[src[e]], 1);
    csr_dst[pos] = dst[e];
}

// ---------------- MFMA GEMM kernels (16x16x16 f16) ----------------

__global__ __launch_bounds__(256) void k_mlp1(const float* __restrict__ xin,
                                              const __fp16* __restrict__ W1h,
                                              const float* __restrict__ b1,
                                              float* __restrict__ X, int N) {
    __shared__ float xs[16 * INCH];
    __shared__ __fp16 wsh[DH * 132];
    int t = threadIdx.x;
    int node0 = blockIdx.x * 16;
    for (int i = t; i < 16 * INCH / 4; i += 256) {
        int r = i >> 5, c = (i & 31) * 4;
        int node = node0 + r;
        f32x4 v = (node < N) ? __builtin_nontemporal_load((const f32x4*)(xin + (size_t)node * INCH + c))
                             : (f32x4){0.f, 0.f, 0.f, 0.f};
        *(f32x4*)&xs[r * INCH + c] = v;
    }
    for (int i = t; i < DH * INCH / 4; i += 256) {
        int r = i >> 5, c = (i & 31) * 4;
        *(uint2*)&wsh[r * 132 + c] = ((const uint2*)W1h)[i];
    }
    __syncthreads();
    int w = t >> 6, lane = t & 63;
    int oc0 = w * 16;
    int rr = lane & 15, g = lane >> 4;
    f32x4 acc = {0.f, 0.f, 0.f, 0.f};
    #pragma unroll
    for (int ks = 0; ks < INCH / 16; ++ks) {
        f32x4 xv = *(const f32x4*)&xs[rr * INCH + ks * 16 + g * 4];
        half4 af = {(__fp16)xv.x, (__fp16)xv.y, (__fp16)xv.z, (__fp16)xv.w};
        half4 bf = *(const half4*)&wsh[(oc0 + rr) * 132 + ks * 16 + g * 4];
        acc = __builtin_amdgcn_mfma_f32_16x16x16f16(af, bf, acc, 0, 0, 0);
    }
    int oc = oc0 + rr;
    float bb = b1[oc];
    #pragma unroll
    for (int r = 0; r < 4; ++r) {
        int node = node0 + g * 4 + r;
        if (node < N) X[(size_t)node * DH + oc] = eluf(acc[r] + bb);
    }
}

// wave per node: layer-0 P/Q -> PQ4 = (p0,p1,q0,q1)
__global__ void k_pq(const float* __restrict__ X, const float* __restrict__ Wsl,
                     float4* __restrict__ PQ4, int N) {
    int wid = (blockIdx.x * blockDim.x + threadIdx.x) >> 6;
    int lane = threadIdx.x & 63;
    if (wid >= N) return;
    float x = X[(size_t)wid * DH + lane];
    float p0 = x * Wsl[lane];
    float q0 = x * Wsl[64 + lane];
    float p1 = x * Wsl[128 + lane];
    float q1 = x * Wsl[192 + lane];
    #pragma unroll
    for (int ofs = 32; ofs; ofs >>= 1) {
        p0 += __shfl_xor(p0, ofs);
        q0 += __shfl_xor(q0, ofs);
        p1 += __shfl_xor(p1, ofs);
        q1 += __shfl_xor(q1, ofs);
    }
    if (lane == 0) PQ4[wid] = make_float4(p0, p1, q0, q1);
}

// XW = X @ kron(Wl,Wr)^T ; f16 stalk-split outputs only
__global__ __launch_bounds__(256) void k_lr(const float* __restrict__ X,
                                            const __fp16* __restrict__ Mlrh_l,
                                            __fp16* __restrict__ XW0h,
                                            __fp16* __restrict__ XW1h, int N) {
    __shared__ float xs[16 * DH];
    __shared__ __fp16 mlh[DH * 68];
    int t = threadIdx.x;
    int node0 = blockIdx.x * 16;
    for (int i = t; i < 16 * DH / 4; i += 256) {
        int r = i >> 4, c = (i & 15) * 4;
        int node = node0 + r;
        f32x4 v = (node < N) ? __builtin_nontemporal_load((const f32x4*)(X + (size_t)node * DH + c))
                             : (f32x4){0.f, 0.f, 0.f, 0.f};
        *(f32x4*)&xs[r * DH + c] = v;
    }
    for (int i = t; i < DH * DH / 4; i += 256) {
        int r = i >> 4, c = (i & 15) * 4;
        *(uint2*)&mlh[r * 68 + c] = ((const uint2*)Mlrh_l)[i];
    }
    __syncthreads();
    int w = t >> 6, lane = t & 63;
    int oc0 = w * 16;
    int rr = lane & 15, g = lane >> 4;
    f32x4 acc = {0.f, 0.f, 0.f, 0.f};
    #pragma unroll
    for (int ks = 0; ks < DH / 16; ++ks) {
        f32x4 xv = *(const f32x4*)&xs[rr * DH + ks * 16 + g * 4];
        half4 af = {(__fp16)xv.x, (__fp16)xv.y, (__fp16)xv.z, (__fp16)xv.w};
        half4 bf = *(const half4*)&mlh[(oc0 + rr) * 68 + ks * 16 + g * 4];
        acc = __builtin_amdgcn_mfma_f32_16x16x16f16(af, bf, acc, 0, 0, 0);
    }
    int oc = oc0 + rr;
    int sp = oc >> 5, c = oc & 31;
    __fp16* __restrict__ XWs = sp ? XW1h : XW0h;
    #pragma unroll
    for (int r = 0; r < 4; ++r) {
        int node = node0 + g * 4 + r;
        if (node < N) XWs[(size_t)node * H + c] = (__fp16)acc[r];
    }
}

__global__ __launch_bounds__(256) void k_out(const float* __restrict__ X,
                                             const __fp16* __restrict__ W2h,
                                             const float* __restrict__ b2,
                                             float* __restrict__ out, int N) {
    __shared__ float xs[32 * DH];
    __shared__ __fp16 w2s[OUTC * 68];
    int t = threadIdx.x;
    int node0 = blockIdx.x * 32;
    for (int i = t; i < 32 * DH / 4; i += 256) {
        int r = i >> 4, c = (i & 15) * 4;
        int node = node0 + r;
        f32x4 v = (node < N) ? __builtin_nontemporal_load((const f32x4*)(X + (size_t)node * DH + c))
                             : (f32x4){0.f, 0.f, 0.f, 0.f};
        *(f32x4*)&xs[r * DH + c] = v;
    }
    for (int i = t; i < OUTC * DH / 4; i += 256) {
        int r = i >> 4, c = (i & 15) * 4;
        *(uint2*)&w2s[r * 68 + c] = ((const uint2*)W2h)[i];
    }
    __syncthreads();
    int w = t >> 6, lane = t & 63;
    int nt = w >> 1;
    int oc0 = (w & 1) * 16;
    int rr = lane & 15, g = lane >> 4;
    f32x4 acc = {0.f, 0.f, 0.f, 0.f};
    #pragma unroll
    for (int ks = 0; ks < DH / 16; ++ks) {
        f32x4 xv = *(const f32x4*)&xs[(nt * 16 + rr) * DH + ks * 16 + g * 4];
        half4 af = {(__fp16)xv.x, (__fp16)xv.y, (__fp16)xv.z, (__fp16)xv.w};
        half4 bf = *(const half4*)&w2s[(oc0 + rr) * 68 + ks * 16 + g * 4];
        acc = __builtin_amdgcn_mfma_f32_16x16x16f16(af, bf, acc, 0, 0, 0);
    }
    int oc = oc0 + rr;
    float bb = b2[oc];
    #pragma unroll
    for (int r = 0; r < 4; ++r) {
        int node = node0 + nt * 16 + g * 4 + r;
        if (node < N) out[(size_t)node * OUTC + oc] = acc[r] + bb;
    }
}

// ---------------- per-layer edge kernels ----------------

// wave per 4 nodes, 16 lanes/node: DGI[u] = (rsqrt(s0+1), rsqrt(s1+1), s0/(s0+1), s1/(s1+1))
__global__ void k_dg(const float4* __restrict__ PQ4, const int* __restrict__ rowptr,
                     const int* __restrict__ csr_dst, float4* __restrict__ DGI, int N) {
    int wid = (blockIdx.x * blockDim.x + threadIdx.x) >> 6;
    int lane = threadIdx.x & 63;
    int nn = lane >> 4, sub = lane & 15;
    int node = wid * 4 + nn;
    if (node >= N) return;
    float4 pqu = PQ4[node];
    int pos = rowptr[node], end = rowptr[node + 1];
    float sx = 0.f, sy = 0.f;
    for (int i = pos + sub; i < end; i += 16) {
        int v = __builtin_nontemporal_load(csr_dst + i);
        float4 pqv = PQ4[v];
        float fx = ftanh(pqu.x + pqv.z);
        float fy = ftanh(pqu.y + pqv.w);
        sx += fx * fx;
        sy += fy * fy;
    }
    #pragma unroll
    for (int ofs = 8; ofs; ofs >>= 1) {
        sx += __shfl_xor(sx, ofs);
        sy += __shfl_xor(sy, ofs);
    }
    if (sub == 0) {
        float i0 = 1.f / (sx + 1.f), i1 = 1.f / (sy + 1.f);
        DGI[node] = make_float4(sqrtf(i0), sqrtf(i1), sx * i0, sy * i1);
    }
}

// wave per node: on-the-fly weights (fast tanh, lane-parallel, shfl-distributed),
// 8 edge slots x 8 channel lanes, both stalks; fused elu/residual + next-layer P/Q
__global__ void k_spmm_fin_pq(const __fp16* __restrict__ XW0h, const __fp16* __restrict__ XW1h,
                              const float4* __restrict__ PQ4, const int* __restrict__ rowptr,
                              const int* __restrict__ csr_dst, const float4* __restrict__ DGI,
                              const float* __restrict__ eps_l, const float* __restrict__ Wsn,
                              float* __restrict__ X, float4* __restrict__ PQ4n, int N) {
    int wid = (blockIdx.x * blockDim.x + threadIdx.x) >> 6;
    int lane = threadIdx.x & 63;
    if (wid >= N) return;
    int q = lane >> 3;        // edge slot 0..7
    int m = lane & 7;         // channel quad within stalk
    float4 pqu = PQ4[wid];
    float4 giu = DGI[wid];
    float dinv0 = giu.x, dinv1 = giu.y;
    int pos = rowptr[wid], end = rowptr[wid + 1];

    float a0x = 0.f, a0y = 0.f, a0z = 0.f, a0w = 0.f;
    float a1x = 0.f, a1y = 0.f, a1z = 0.f, a1w = 0.f;

    for (int chunk = pos; chunk < end; chunk += 64) {
        // lane-parallel weight precompute: lane handles edge chunk+lane
        int myidx = chunk + lane;
        int dmy = 0;
        float w0my = 0.f, w1my = 0.f;
        if (myidx < end) {
            dmy = __builtin_nontemporal_load(csr_dst + myidx);
            float4 pqd = PQ4[dmy];
            float4 gid = DGI[dmy];
            float ff0 = ftanh(pqu.x + pqd.z), fb0 = ftanh(pqd.x + pqu.z);
            float ff1 = ftanh(pqu.y + pqd.w), fb1 = ftanh(pqd.y + pqu.w);
            w0my = -ff0 * fb0 * dinv0 * gid.x;
            w1my = -ff1 * fb1 * dinv1 * gid.y;
        }
        int lim = end - chunk; if (lim > 64) lim = 64;
        for (int b = 0; b < lim; b += 8) {
            int sl = b + q;
            int d      = __shfl(dmy, sl);
            float w0e  = __shfl(w0my, sl);   // 0 for sl >= row length
            float w1e  = __shfl(w1my, sl);
            half4 g0 = *(const half4*)(XW0h + (size_t)d * H + m * 4);
            half4 g1 = *(const half4*)(XW1h + (size_t)d * H + m * 4);
            a0x += w0e * (float)g0.x; a0y += w0e * (float)g0.y;
            a0z += w0e * (float)g0.z; a0w += w0e * (float)g0.w;
            a1x += w1e * (float)g1.x; a1y += w1e * (float)g1.y;
            a1z += w1e * (float)g1.z; a1w += w1e * (float)g1.w;
        }
    }
    // reduce across 8 edge slots
    #pragma unroll
    for (int ofs = 8; ofs <= 32; ofs <<= 1) {
        a0x += __shfl_xor(a0x, ofs); a0y += __shfl_xor(a0y, ofs);
        a0z += __shfl_xor(a0z, ofs); a0w += __shfl_xor(a0w, ofs);
        a1x += __shfl_xor(a1x, ofs); a1y += __shfl_xor(a1y, ofs);
        a1z += __shfl_xor(a1z, ofs); a1w += __shfl_xor(a1w, ofs);
    }
    if (q == 0) {
        float diag0 = giu.z;
        float diag1 = giu.w;
        half4 xw0 = *(const half4*)(XW0h + (size_t)wid * H + m * 4);
        half4 xw1 = *(const half4*)(XW1h + (size_t)wid * H + m * 4);
        size_t b0 = (size_t)wid * DH + m * 4;
        size_t b1 = b0 + 32;
        float coeff0 = 1.f + tanhf(eps_l[0]);
        float coeff1 = 1.f + tanhf(eps_l[1]);
        f32x4 xo0 = __builtin_nontemporal_load((const f32x4*)(X + b0));
        f32x4 xo1 = __builtin_nontemporal_load((const f32x4*)(X + b1));
        f32x4 xn0, xn1;
        xn0.x = coeff0 * xo0.x - eluf(diag0 * (float)xw0.x + a0x);
        xn0.y = coeff0 * xo0.y - eluf(diag0 * (float)xw0.y + a0y);
        xn0.z = coeff0 * xo0.z - eluf(diag0 * (float)xw0.z + a0z);
        xn0.w = coeff0 * xo0.w - eluf(diag0 * (float)xw0.w + a0w);
        xn1.x = coeff1 * xo1.x - eluf(diag1 * (float)xw1.x + a1x);
        xn1.y = coeff1 * xo1.y - eluf(diag1 * (float)xw1.y + a1y);
        xn1.z = coeff1 * xo1.z - eluf(diag1 * (float)xw1.z + a1z);
        xn1.w = coeff1 * xo1.w - eluf(diag1 * (float)xw1.w + a1w);
        __builtin_nontemporal_store(xn0, (f32x4*)(X + b0));
        __builtin_nontemporal_store(xn1, (f32x4*)(X + b1));
        if (Wsn) {
            f32x4 wa0 = *(const f32x4*)(Wsn + m * 4);
            f32x4 wa1 = *(const f32x4*)(Wsn + 32 + m * 4);
            f32x4 wb0 = *(const f32x4*)(Wsn + 64 + m * 4);
            f32x4 wb1 = *(const f32x4*)(Wsn + 96 + m * 4);
            f32x4 wc0 = *(const f32x4*)(Wsn + 128 + m * 4);
            f32x4 wc1 = *(const f32x4*)(Wsn + 160 + m * 4);
            f32x4 wd0 = *(const f32x4*)(Wsn + 192 + m * 4);
            f32x4 wd1 = *(const f32x4*)(Wsn + 224 + m * 4);
            float p0 = xn0.x * wa0.x + xn0.y * wa0.y + xn0.z * wa0.z + xn0.w * wa0.w
                     + xn1.x * wa1.x + xn1.y * wa1.y + xn1.z * wa1.z + xn1.w * wa1.w;
            float q0 = xn0.x * wb0.x + xn0.y * wb0.y + xn0.z * wb0.z + xn0.w * wb0.w
                     + xn1.x * wb1.x + xn1.y * wb1.y + xn1.z * wb1.z + xn1.w * wb1.w;
            float p1 = xn0.x * wc0.x + xn0.y * wc0.y + xn0.z * wc0.z + xn0.w * wc0.w
                     + xn1.x * wc1.x + xn1.y * wc1.y + xn1.z * wc1.z + xn1.w * wc1.w;
            float q1 = xn0.x * wd0.x + xn0.y * wd0.y + xn0.z * wd0.z + xn0.w * wd0.w
                     + xn1.x * wd1.x + xn1.y * wd1.y + xn1.z * wd1.z + xn1.w * wd1.w;
            #pragma unroll
            for (int ofs = 1; ofs < 8; ofs <<= 1) {
                p0 += __shfl_xor(p0, ofs);
                q0 += __shfl_xor(q0, ofs);
                p1 += __shfl_xor(p1, ofs);
                q1 += __shfl_xor(q1, ofs);
            }
            if (m == 0) PQ4n[wid] = make_float4(p0, p1, q0, q1);
        }
    }
}

extern "C" void kernel_launch(void* const* d_in, const int* in_sizes, int n_in,
                              void* d_out, int out_size, void* d_ws, size_t ws_size,
                              hipStream_t stream) {
    const float* xin    = (const float*)d_in[0];
    const int*   ei     = (const int*)d_in[1];
    const float* W1     = (const float*)d_in[2];
    const float* b1     = (const float*)d_in[3];
    const float* Wsheaf = (const float*)d_in[4];
    const float* Wleft  = (const float*)d_in[5];
    const float* Wright = (const float*)d_in[6];
    const float* eps    = (const float*)d_in[7];
    const float* W2     = (const float*)d_in[8];
    const float* b2     = (const float*)d_in[9];
    float* out = (float*)d_out;

    int N = in_sizes[0] / INCH;
    int E = in_sizes[1] / 2;
    const int* src = ei;
    const int* dst = ei + E;

    size_t off = 0;
    auto alloc = [&](size_t nbytes) {
        char* p = (char*)d_ws + off;
        off += (nbytes + 255) & ~(size_t)255;
        return p;
    };
    float*   X       = (float*)alloc((size_t)N * DH * 4);
    __fp16*  XW0h    = (__fp16*)alloc((size_t)N * H * 2);
    __fp16*  XW1h    = (__fp16*)alloc((size_t)N * H * 2);
    float4*  DGI     = (float4*)alloc((size_t)N * 16);
    float4*  PQ4a    = (float4*)alloc((size_t)N * 16);
    float4*  PQ4b    = (float4*)alloc((size_t)N * 16);
    int*     deg     = (int*)alloc((size_t)N * 4);
    int*     rowptr  = (int*)alloc(((size_t)N + 1) * 4);
    int*     cur     = (int*)alloc((size_t)N * 4);
    int*     csr_dst = (int*)alloc((size_t)E * 4);
    int*     bsum    = (int*)alloc(4096);
    __fp16*  W1h     = (__fp16*)alloc((size_t)DH * INCH * 2);
    __fp16*  W2h     = (__fp16*)alloc((size_t)OUTC * DH * 2);
    __fp16*  Mlrh    = (__fp16*)alloc((size_t)LAYERS * DH * DH * 2);

    int B = (N + 1023) / 1024;

    // one-time prep + CSR build
    int prep_total = DH * INCH + OUTC * DH + LAYERS * DH * DH;
    k_prep<<<(prep_total + 255) / 256, 256, 0, stream>>>(W1, W2, Wleft, Wright, W1h, W2h, Mlrh);
    hipMemsetAsync(deg, 0, (size_t)N * sizeof(int), stream);
    k_hist<<<(E + 255) / 256, 256, 0, stream>>>(src, deg, E);
    k_bsum<<<B, 256, 0, stream>>>(deg, bsum, N);
    k_scan_small<<<1, 64, 0, stream>>>(bsum, B);
    k_scan_final<<<B, 256, 0, stream>>>(deg, bsum, rowptr, cur, N);
    k_scatter<<<(E + 255) / 256, 256, 0, stream>>>(src, dst, cur, csr_dst, E);

    k_mlp1<<<(N + 15) / 16, 256, 0, stream>>>(xin, W1h, b1, X, N);
    k_pq<<<(N + 3) / 4, 256, 0, stream>>>(X, Wsheaf, PQ4a, N);

    float4* PQcur = PQ4a;
    float4* PQnext = PQ4b;
    for (int l = 0; l < LAYERS; ++l) {
        k_dg<<<(N + 15) / 16, 256, 0, stream>>>(PQcur, rowptr, csr_dst, DGI, N);
        k_lr<<<(N + 15) / 16, 256, 0, stream>>>(X, Mlrh + (size_t)l * DH * DH, XW0h, XW1h, N);
        const float* Wsn = (l + 1 < LAYERS) ? (Wsheaf + (l + 1) * 2 * INCH) : nullptr;
        k_spmm_fin_pq<<<(N + 3) / 4, 256, 0, stream>>>(XW0h, XW1h, PQcur, rowptr, csr_dst,
                                                       DGI, eps + l * 2, Wsn, X, PQnext, N);
        float4* tmp = PQcur; PQcur = PQnext; PQnext = tmp;
    }

    k_out<<<(N + 31) / 32, 256, 0, stream>>>(X, W2h, b2, out, N);
}